// Round 9
// baseline (424.928 us; speedup 1.0000x reference)
//
#include <hip/hip_runtime.h>
#include <stdint.h>

#define N_NODES 100000
#define KNBR 16
#define ALPHA 0.2f

typedef __attribute__((ext_vector_type(8))) short bf16x8;
typedef __attribute__((ext_vector_type(4))) float f32x4;
typedef __attribute__((ext_vector_type(4))) unsigned int u32x4;
typedef unsigned short u16;
typedef unsigned int u32;
typedef unsigned char u8;

static __device__ __forceinline__ u16 f2bf(float f) {
  u32 u = __builtin_bit_cast(u32, f);
  u += 0x7fffu + ((u >> 16) & 1u);   // round-to-nearest-even
  return (u16)(u >> 16);
}

// ---- Kernel 1: W -> Wb in MFMA B-fragment order ----
// frag(ks, ct): lane l, elem i = W[ks*32 + (l>>4)*8 + i][ct*16 + (l&15)]
__global__ __launch_bounds__(256) void prep_w_kernel(const float* __restrict__ W,
                                                     u16* __restrict__ Wb) {
  const int t = blockIdx.x * 256 + threadIdx.x;  // 0..8191
  const int l = t & 63;
  const int ct = (t >> 6) & 15;
  const int ks = t >> 10;
  const int colbase = ct * 16 + (l & 15);
  const int k0 = ks * 32 + (l >> 4) * 8;
  u32 wq[4];
#pragma unroll
  for (int q = 0; q < 4; ++q) {
    const u16 b0 = f2bf(W[(k0 + 2 * q) * 256 + colbase]);
    const u16 b1 = f2bf(W[(k0 + 2 * q + 1) * 256 + colbase]);
    wq[q] = (u32)b0 | ((u32)b1 << 16);
  }
  u32x4 o = {wq[0], wq[1], wq[2], wq[3]};
  *(u32x4*)(Wb + (size_t)t * 8) = o;
}

// ---- Kernel 2: GEMM Y = h @ W + per-row int8 quant, 64 rows per block ----
__global__ __launch_bounds__(256, 3) void gemm_kernel(const float* __restrict__ h,
                                                      const u16* __restrict__ Wb,
                                                      u8* __restrict__ Yq,
                                                      float* __restrict__ scale) {
  __shared__ __align__(16) u16 aS[64 * 256];   // 32 KB: bf16 A-tile, later u8 quant tile
  __shared__ float redS[4][64];
  __shared__ float invSS[64];
  const int tid = threadIdx.x;
  const int blk = blockIdx.x;
  const size_t base = (size_t)blk * (64 * 256);

  // stage 64x256 fp32 -> bf16 LDS (swizzled); NT loads (h streamed once)
#pragma unroll
  for (int i = 0; i < 16; ++i) {
    const int flat = i * 1024 + tid * 4;       // float index in tile
    const int row = flat >> 8, d0 = flat & 255;
    f32x4 v = {0.f, 0.f, 0.f, 0.f};
    if (blk * 64 + row < N_NODES)
      v = __builtin_nontemporal_load((const f32x4*)(h + base + flat));
    uint2 o;
    o.x = (u32)f2bf(v[0]) | ((u32)f2bf(v[1]) << 16);
    o.y = (u32)f2bf(v[2]) | ((u32)f2bf(v[3]) << 16);
    *(uint2*)((char*)aS + row * 512 + ((d0 * 2) ^ ((row & 7) << 4))) = o;
  }
  __syncthreads();

  // MFMA: A = aS[64x256], B = Wb fragments (L2-resident). Wave wv owns 64 cols.
  const int l = tid & 63, wv = tid >> 6;
  const int l15 = l & 15, lg = l >> 4;
  f32x4 acc[4][4] = {};
  const u32x4* wbL = ((const u32x4*)Wb) + (size_t)(wv * 4) * 64 + l;
  const char* aggB = (const char*)aS;
  const int rb0 = l15 * 512;
  const int xm = (l15 & 7) << 4;
#pragma unroll 2
  for (int ks = 0; ks < 8; ++ks) {
    const int offk = ((ks * 64) + lg * 16) ^ xm;
    bf16x8 a[4];
#pragma unroll
    for (int rt = 0; rt < 4; ++rt)
      a[rt] = *(const bf16x8*)(aggB + rt * 8192 + rb0 + offk);
#pragma unroll
    for (int c = 0; c < 4; ++c) {
      const u32x4 bw = wbL[ks * 1024 + c * 64];
      const bf16x8 b = __builtin_bit_cast(bf16x8, bw);
#pragma unroll
      for (int rt = 0; rt < 4; ++rt)
        acc[rt][c] = __builtin_amdgcn_mfma_f32_16x16x32_bf16(a[rt], b, acc[rt][c], 0, 0, 0);
    }
  }

  // rowmax -> per-row scale
#pragma unroll
  for (int rt = 0; rt < 4; ++rt)
#pragma unroll
    for (int j = 0; j < 4; ++j) {
      float m = 0.f;
#pragma unroll
      for (int c = 0; c < 4; ++c) m = fmaxf(m, fabsf(acc[rt][c][j]));
      m = fmaxf(m, __shfl_xor(m, 1)); m = fmaxf(m, __shfl_xor(m, 2));
      m = fmaxf(m, __shfl_xor(m, 4)); m = fmaxf(m, __shfl_xor(m, 8));
      redS[wv][rt * 16 + lg * 4 + j] = m;
    }
  __syncthreads();
  if (tid < 64) {
    float m = fmaxf(fmaxf(redS[0][tid], redS[1][tid]),
                    fmaxf(redS[2][tid], redS[3][tid]));
    m = fmaxf(m, 1e-20f);
    if (blk * 64 + tid < N_NODES) scale[blk * 64 + tid] = m * (1.0f / 127.0f);
    invSS[tid] = 127.0f / m;
  }
  __syncthreads();

  // quantize into LDS u8 tile (XOR-swizzled)
  u8* qS = (u8*)aS;
#pragma unroll
  for (int rt = 0; rt < 4; ++rt)
#pragma unroll
    for (int j = 0; j < 4; ++j) {
      const int r = rt * 16 + lg * 4 + j;
      const float inv = invSS[r];
      const int sw = ((r >> 2) & 7) << 5;
#pragma unroll
      for (int c = 0; c < 4; ++c) {
        float q = rintf(acc[rt][c][j] * inv);
        q = fminf(127.f, fmaxf(-127.f, q));
        qS[r * 256 + ((wv * 64 + c * 16 + l15) ^ sw)] = (u8)((int)q + 128);
      }
    }
  __syncthreads();

  // coalesced 16B stores of the 16KB quant tile
  const u32x4* q4 = (const u32x4*)aS;
  u32x4* yg = (u32x4*)(Yq + (size_t)blk * 16384);
#pragma unroll
  for (int qq = 0; qq < 4; ++qq) {
    const int f = qq * 256 + tid;              // u32x4 piece index in tile
    const int row = f >> 4;
    const int colx = ((f & 15) * 16) ^ (((row >> 2) & 7) << 5);
    if (blk * 64 + row < N_NODES)
      __builtin_nontemporal_store(q4[(row * 256 + colx) >> 4], &yg[f]);
  }
}

// ---- Kernel 3: gather-mean (int8 Y) + leaky + L2-normalize, fused ----
// 16 lanes per node (16 B/lane, full 256 B row per quarter-wave); indices and
// gathered scales staged in LDS per block (broadcast reads in the hot loop).
__global__ __launch_bounds__(256, 5) void gather_kernel(const u8* __restrict__ Yq,
                                                        const float* __restrict__ scale,
                                                        const int* __restrict__ nbr,
                                                        float* __restrict__ out) {
  __shared__ int nbrS[16][16];
  __shared__ float sS[16][17];
  const int tid = threadIdx.x;
  const int nb0 = blockIdx.x * 16;

  {  // stage 16 nodes x 16 neighbor indices (coalesced) + their scales (scattered)
    const int n = tid >> 4, j = tid & 15;
    const int idx = nbr[(nb0 + n) * KNBR + j];
    nbrS[n][j] = idx;
    sS[n][j] = scale[idx];
    if (tid < 16) sS[tid][16] = scale[nb0 + tid];   // self scale
  }
  __syncthreads();

  const int lane = tid & 63, wv = tid >> 6;
  const int qd = lane >> 4, l15 = lane & 15;
  const int nl = wv * 4 + qd;                 // local node 0..15
  const int node = nb0 + nl;
  const u32x4* yb = (const u32x4*)Yq;         // 16 B units: row*16 + l15

  u32x4 v[17];
#pragma unroll
  for (int j = 0; j < 16; ++j)
    v[j] = yb[(size_t)nbrS[nl][j] * 16 + l15];
  v[16] = yb[(size_t)node * 16 + l15];        // self (sequential, cheap)

  float a[16];
#pragma unroll
  for (int k = 0; k < 16; ++k) a[k] = 0.f;
  float S = 0.f;
#pragma unroll
  for (int j = 0; j < 17; ++j) {
    const float sj = sS[nl][j];
    S += sj;
    const u32x4 w = v[j];
#pragma unroll
    for (int k = 0; k < 4; ++k) {
      float f0, f1, f2, f3;
      asm("v_cvt_f32_ubyte0 %0, %1" : "=v"(f0) : "v"(w[k]));
      asm("v_cvt_f32_ubyte1 %0, %1" : "=v"(f1) : "v"(w[k]));
      asm("v_cvt_f32_ubyte2 %0, %1" : "=v"(f2) : "v"(w[k]));
      asm("v_cvt_f32_ubyte3 %0, %1" : "=v"(f3) : "v"(w[k]));
      a[k * 4 + 0] = fmaf(sj, f0, a[k * 4 + 0]);
      a[k * 4 + 1] = fmaf(sj, f1, a[k * 4 + 1]);
      a[k * 4 + 2] = fmaf(sj, f2, a[k * 4 + 2]);
      a[k * 4 + 3] = fmaf(sj, f3, a[k * 4 + 3]);
    }
  }

  const float sc = 1.0f / 17.0f, bias = 128.0f * S;
  float ss = 0.f;
#pragma unroll
  for (int k = 0; k < 16; ++k) {
    float z = (a[k] - bias) * sc;
    z = (z >= 0.f) ? z : ALPHA * z;
    a[k] = z;
    ss += z * z;
  }
  // reduce over the 16 lanes of this node
  ss += __shfl_xor(ss, 1); ss += __shfl_xor(ss, 2);
  ss += __shfl_xor(ss, 4); ss += __shfl_xor(ss, 8);
  const float inv = 1.0f / fmaxf(sqrtf(ss), 1e-12f);

  float* op = out + (size_t)node * 256 + l15 * 16;
#pragma unroll
  for (int k = 0; k < 4; ++k) {
    f32x4 o = {a[k * 4 + 0] * inv, a[k * 4 + 1] * inv,
               a[k * 4 + 2] * inv, a[k * 4 + 3] * inv};
    __builtin_nontemporal_store(o, (f32x4*)(op + k * 4));
  }
}

extern "C" void kernel_launch(void* const* d_in, const int* in_sizes, int n_in,
                              void* d_out, int out_size, void* d_ws, size_t ws_size,
                              hipStream_t stream) {
  const float* h = (const float*)d_in[0];
  const int* nbr = (const int*)d_in[1];
  const float* W = (const float*)d_in[2];
  float* out = (float*)d_out;

  char* ws = (char*)d_ws;
  u16* Wb = (u16*)ws;                               // 128 KB fragment-ordered W
  float* scale = (float*)(ws + (1 << 17));          // ~400 KB f32 row scales
  u8* Yq = (u8*)(ws + (1 << 20));                   // 25.6 MB int8 Y

  prep_w_kernel<<<32, 256, 0, stream>>>(W, Wb);
  gemm_kernel<<<(N_NODES + 63) / 64, 256, 0, stream>>>(h, Wb, Yq, scale);
  gather_kernel<<<N_NODES / 16, 256, 0, stream>>>(Yq, scale, nbr, out);
}

// Round 10
// 118.026 us; speedup vs baseline: 3.6003x; 3.6003x over previous
//
#include <hip/hip_runtime.h>
#include <stdint.h>

#define N_NODES 100000
#define KNBR 16
#define ALPHA 0.2f

typedef __attribute__((ext_vector_type(8))) short bf16x8;
typedef __attribute__((ext_vector_type(4))) float f32x4;
typedef __attribute__((ext_vector_type(4))) unsigned int u32x4;
typedef unsigned short u16;
typedef unsigned int u32;
typedef unsigned char u8;

static __device__ __forceinline__ u16 f2bf(float f) {
  u32 u = __builtin_bit_cast(u32, f);
  u += 0x7fffu + ((u >> 16) & 1u);   // round-to-nearest-even
  return (u16)(u >> 16);
}

// ---- Kernel 1: W -> Wb in MFMA B-fragment order ----
// frag(ks, ct): lane l, elem i = W[ks*32 + (l>>4)*8 + i][ct*16 + (l&15)]
__global__ __launch_bounds__(256) void prep_w_kernel(const float* __restrict__ W,
                                                     u16* __restrict__ Wb) {
  const int t = blockIdx.x * 256 + threadIdx.x;  // 0..8191
  const int l = t & 63;
  const int ct = (t >> 6) & 15;
  const int ks = t >> 10;
  const int colbase = ct * 16 + (l & 15);
  const int k0 = ks * 32 + (l >> 4) * 8;
  u32 wq[4];
#pragma unroll
  for (int q = 0; q < 4; ++q) {
    const u16 b0 = f2bf(W[(k0 + 2 * q) * 256 + colbase]);
    const u16 b1 = f2bf(W[(k0 + 2 * q + 1) * 256 + colbase]);
    wq[q] = (u32)b0 | ((u32)b1 << 16);
  }
  u32x4 o = {wq[0], wq[1], wq[2], wq[3]};
  *(u32x4*)(Wb + (size_t)t * 8) = o;
}

// ---- Kernel 2: GEMM Y = h @ W + per-row int8 quant, 64 rows per block ----
__global__ __launch_bounds__(256, 3) void gemm_kernel(const float* __restrict__ h,
                                                      const u16* __restrict__ Wb,
                                                      u8* __restrict__ Yq,
                                                      float* __restrict__ scale) {
  __shared__ __align__(16) u16 aS[64 * 256];   // 32 KB: bf16 A-tile, later u8 quant tile
  __shared__ float redS[4][64];
  __shared__ float invSS[64];
  const int tid = threadIdx.x;
  const int blk = blockIdx.x;
  const size_t base = (size_t)blk * (64 * 256);

  // stage 64x256 fp32 -> bf16 LDS (swizzled); NT loads (h streamed once)
#pragma unroll
  for (int i = 0; i < 16; ++i) {
    const int flat = i * 1024 + tid * 4;       // float index in tile
    const int row = flat >> 8, d0 = flat & 255;
    f32x4 v = {0.f, 0.f, 0.f, 0.f};
    if (blk * 64 + row < N_NODES)
      v = __builtin_nontemporal_load((const f32x4*)(h + base + flat));
    uint2 o;
    o.x = (u32)f2bf(v[0]) | ((u32)f2bf(v[1]) << 16);
    o.y = (u32)f2bf(v[2]) | ((u32)f2bf(v[3]) << 16);
    *(uint2*)((char*)aS + row * 512 + ((d0 * 2) ^ ((row & 7) << 4))) = o;
  }
  __syncthreads();

  // MFMA: A = aS[64x256], B = Wb fragments (L2-resident). Wave wv owns 64 cols.
  const int l = tid & 63, wv = tid >> 6;
  const int l15 = l & 15, lg = l >> 4;
  f32x4 acc[4][4] = {};
  const u32x4* wbL = ((const u32x4*)Wb) + (size_t)(wv * 4) * 64 + l;
  const char* aggB = (const char*)aS;
  const int rb0 = l15 * 512;
  const int xm = (l15 & 7) << 4;
#pragma unroll 2
  for (int ks = 0; ks < 8; ++ks) {
    const int offk = ((ks * 64) + lg * 16) ^ xm;
    bf16x8 a[4];
#pragma unroll
    for (int rt = 0; rt < 4; ++rt)
      a[rt] = *(const bf16x8*)(aggB + rt * 8192 + rb0 + offk);
#pragma unroll
    for (int c = 0; c < 4; ++c) {
      const u32x4 bw = wbL[ks * 1024 + c * 64];
      const bf16x8 b = __builtin_bit_cast(bf16x8, bw);
#pragma unroll
      for (int rt = 0; rt < 4; ++rt)
        acc[rt][c] = __builtin_amdgcn_mfma_f32_16x16x32_bf16(a[rt], b, acc[rt][c], 0, 0, 0);
    }
  }

  // rowmax -> per-row scale
#pragma unroll
  for (int rt = 0; rt < 4; ++rt)
#pragma unroll
    for (int j = 0; j < 4; ++j) {
      float m = 0.f;
#pragma unroll
      for (int c = 0; c < 4; ++c) m = fmaxf(m, fabsf(acc[rt][c][j]));
      m = fmaxf(m, __shfl_xor(m, 1)); m = fmaxf(m, __shfl_xor(m, 2));
      m = fmaxf(m, __shfl_xor(m, 4)); m = fmaxf(m, __shfl_xor(m, 8));
      redS[wv][rt * 16 + lg * 4 + j] = m;
    }
  __syncthreads();
  if (tid < 64) {
    float m = fmaxf(fmaxf(redS[0][tid], redS[1][tid]),
                    fmaxf(redS[2][tid], redS[3][tid]));
    m = fmaxf(m, 1e-20f);
    if (blk * 64 + tid < N_NODES) scale[blk * 64 + tid] = m * (1.0f / 127.0f);
    invSS[tid] = 127.0f / m;
  }
  __syncthreads();

  // quantize into LDS u8 tile (XOR-swizzled)
  u8* qS = (u8*)aS;
#pragma unroll
  for (int rt = 0; rt < 4; ++rt)
#pragma unroll
    for (int j = 0; j < 4; ++j) {
      const int r = rt * 16 + lg * 4 + j;
      const float inv = invSS[r];
      const int sw = ((r >> 2) & 7) << 5;
#pragma unroll
      for (int c = 0; c < 4; ++c) {
        float q = rintf(acc[rt][c][j] * inv);
        q = fminf(127.f, fmaxf(-127.f, q));
        qS[r * 256 + ((wv * 64 + c * 16 + l15) ^ sw)] = (u8)((int)q + 128);
      }
    }
  __syncthreads();

  // coalesced 16B stores of the 16KB quant tile
  const u32x4* q4 = (const u32x4*)aS;
  u32x4* yg = (u32x4*)(Yq + (size_t)blk * 16384);
#pragma unroll
  for (int qq = 0; qq < 4; ++qq) {
    const int f = qq * 256 + tid;              // u32x4 piece index in tile
    const int row = f >> 4;
    const int colx = ((f & 15) * 16) ^ (((row >> 2) & 7) << 5);
    if (blk * 64 + row < N_NODES)
      __builtin_nontemporal_store(q4[(row * 256 + colx) >> 4], &yg[f]);
  }
}

// ---- Kernel 3: gather-mean (int8 Y-space) + leaky + L2-normalize ----
// R5 structure verbatim: one wave per node, 4B/lane, 17 loads in flight,
// VGPR ~28, occupancy ~75%. Proven 70 us (fill-BW wall ~2.8 TB/s).
__global__ __launch_bounds__(256) void gather_kernel(const u8* __restrict__ Yq,
                                                     const float* __restrict__ scale,
                                                     const int* __restrict__ nbr,
                                                     float* __restrict__ out) {
  const int tid = threadIdx.x;
  const int lane = tid & 63, wv = tid >> 6;
  const int node = __builtin_amdgcn_readfirstlane(blockIdx.x * 4 + wv);

  const int il = nbr[node * KNBR + (lane & 15)];
  const float vscale = scale[il];
  const float sself = scale[node];
  const u32* yb = (const u32*)Yq;

  u32 v[17];
  v[0] = yb[(size_t)node * 64 + lane];
#pragma unroll
  for (int j = 0; j < 16; ++j) {
    const int r = __builtin_amdgcn_readlane(il, j);
    v[j + 1] = yb[(size_t)r * 64 + lane];
  }

  float a0, a1, a2, a3, S = sself;
  {
    float f0, f1, f2, f3;
    asm("v_cvt_f32_ubyte0 %0, %1" : "=v"(f0) : "v"(v[0]));
    asm("v_cvt_f32_ubyte1 %0, %1" : "=v"(f1) : "v"(v[0]));
    asm("v_cvt_f32_ubyte2 %0, %1" : "=v"(f2) : "v"(v[0]));
    asm("v_cvt_f32_ubyte3 %0, %1" : "=v"(f3) : "v"(v[0]));
    a0 = sself * f0; a1 = sself * f1; a2 = sself * f2; a3 = sself * f3;
  }
#pragma unroll
  for (int j = 0; j < 16; ++j) {
    const float s = __builtin_bit_cast(
        float, __builtin_amdgcn_readlane(__builtin_bit_cast(int, vscale), j));
    float f0, f1, f2, f3;
    asm("v_cvt_f32_ubyte0 %0, %1" : "=v"(f0) : "v"(v[j + 1]));
    asm("v_cvt_f32_ubyte1 %0, %1" : "=v"(f1) : "v"(v[j + 1]));
    asm("v_cvt_f32_ubyte2 %0, %1" : "=v"(f2) : "v"(v[j + 1]));
    asm("v_cvt_f32_ubyte3 %0, %1" : "=v"(f3) : "v"(v[j + 1]));
    S += s;
    a0 = fmaf(s, f0, a0); a1 = fmaf(s, f1, a1);
    a2 = fmaf(s, f2, a2); a3 = fmaf(s, f3, a3);
  }
  const float sc = 1.0f / 17.0f, bias = 128.0f * S;
  a0 = (a0 - bias) * sc; a1 = (a1 - bias) * sc;
  a2 = (a2 - bias) * sc; a3 = (a3 - bias) * sc;
  a0 = (a0 >= 0.f) ? a0 : ALPHA * a0;
  a1 = (a1 >= 0.f) ? a1 : ALPHA * a1;
  a2 = (a2 >= 0.f) ? a2 : ALPHA * a2;
  a3 = (a3 >= 0.f) ? a3 : ALPHA * a3;

  float ss = a0 * a0 + a1 * a1 + a2 * a2 + a3 * a3;
  ss += __shfl_xor(ss, 1);  ss += __shfl_xor(ss, 2);
  ss += __shfl_xor(ss, 4);  ss += __shfl_xor(ss, 8);
  ss += __shfl_xor(ss, 16); ss += __shfl_xor(ss, 32);
  const float inv = 1.0f / fmaxf(sqrtf(ss), 1e-12f);

  f32x4 o = {a0 * inv, a1 * inv, a2 * inv, a3 * inv};
  __builtin_nontemporal_store(o, (f32x4*)(out + (size_t)node * 256 + lane * 4));
}

extern "C" void kernel_launch(void* const* d_in, const int* in_sizes, int n_in,
                              void* d_out, int out_size, void* d_ws, size_t ws_size,
                              hipStream_t stream) {
  const float* h = (const float*)d_in[0];
  const int* nbr = (const int*)d_in[1];
  const float* W = (const float*)d_in[2];
  float* out = (float*)d_out;

  char* ws = (char*)d_ws;
  u16* Wb = (u16*)ws;                               // 128 KB fragment-ordered W
  float* scale = (float*)(ws + (1 << 17));          // ~400 KB f32 row scales
  u8* Yq = (u8*)(ws + (1 << 20));                   // 25.6 MB int8 Y

  prep_w_kernel<<<32, 256, 0, stream>>>(W, Wb);
  gemm_kernel<<<(N_NODES + 63) / 64, 256, 0, stream>>>(h, Wb, Yq, scale);
  gather_kernel<<<N_NODES / 4, 256, 0, stream>>>(Yq, scale, nbr, out);
}

// Round 11
// 114.307 us; speedup vs baseline: 3.7174x; 1.0325x over previous
//
#include <hip/hip_runtime.h>
#include <stdint.h>

#define N_NODES 100000
#define KNBR 16
#define ALPHA 0.2f

typedef __attribute__((ext_vector_type(8))) short bf16x8;
typedef __attribute__((ext_vector_type(4))) float f32x4;
typedef __attribute__((ext_vector_type(4))) unsigned int u32x4;
typedef unsigned short u16;
typedef unsigned int u32;
typedef unsigned char u8;

static __device__ __forceinline__ u16 f2bf(float f) {
  u32 u = __builtin_bit_cast(u32, f);
  u += 0x7fffu + ((u >> 16) & 1u);   // round-to-nearest-even
  return (u16)(u >> 16);
}

// ---- Kernel 1: W -> Wb in MFMA B-fragment order ----
// frag(ks, ct): lane l, elem i = W[ks*32 + (l>>4)*8 + i][ct*16 + (l&15)]
__global__ __launch_bounds__(256) void prep_w_kernel(const float* __restrict__ W,
                                                     u16* __restrict__ Wb) {
  const int t = blockIdx.x * 256 + threadIdx.x;  // 0..8191
  const int l = t & 63;
  const int ct = (t >> 6) & 15;
  const int ks = t >> 10;
  const int colbase = ct * 16 + (l & 15);
  const int k0 = ks * 32 + (l >> 4) * 8;
  u32 wq[4];
#pragma unroll
  for (int q = 0; q < 4; ++q) {
    const u16 b0 = f2bf(W[(k0 + 2 * q) * 256 + colbase]);
    const u16 b1 = f2bf(W[(k0 + 2 * q + 1) * 256 + colbase]);
    wq[q] = (u32)b0 | ((u32)b1 << 16);
  }
  u32x4 o = {wq[0], wq[1], wq[2], wq[3]};
  *(u32x4*)(Wb + (size_t)t * 8) = o;
}

// ---- Kernel 2: GEMM Y = h @ W + per-row int8 quant, 32 rows per block ----
// Staging via v_cvt_pk_bf16_f32 (1 VALU / 2 elems); quant via fma+clamp+trunc.
__global__ __launch_bounds__(256, 4) void gemm_kernel(const float* __restrict__ h,
                                                      const u16* __restrict__ Wb,
                                                      u8* __restrict__ Yq,
                                                      float* __restrict__ scale) {
  __shared__ __align__(16) u16 aS[32 * 256];   // 16 KB: bf16 A-tile, later u8 quant tile
  __shared__ float redS[4][32];
  __shared__ float invSS[32];
  const int tid = threadIdx.x;
  const int blk = blockIdx.x;
  const size_t base = (size_t)blk * (32 * 256);

  // stage 32x256 fp32 -> bf16 LDS (swizzled); NT loads (h streamed once)
#pragma unroll
  for (int i = 0; i < 8; ++i) {
    const int flat = i * 1024 + tid * 4;       // float index in tile
    const int row = flat >> 8, d0 = flat & 255;
    const f32x4 v = __builtin_nontemporal_load((const f32x4*)(h + base + flat));
    uint2 o;
    asm("v_cvt_pk_bf16_f32 %0, %1, %2" : "=v"(o.x) : "v"(v[0]), "v"(v[1]));
    asm("v_cvt_pk_bf16_f32 %0, %1, %2" : "=v"(o.y) : "v"(v[2]), "v"(v[3]));
    *(uint2*)((char*)aS + row * 512 + ((d0 * 2) ^ ((row & 7) << 4))) = o;
  }
  __syncthreads();

  // MFMA: A = aS[32x256], B = Wb fragments (L2-resident)
  const int l = tid & 63, wv = tid >> 6;
  const int l15 = l & 15, lg = l >> 4;
  f32x4 acc[2][4] = {};
  const u32x4* wbL = ((const u32x4*)Wb) + (size_t)(wv * 4) * 64 + l;
  const char* aggB = (const char*)aS;
  const int rb0 = l15 * 512;
  const int xm = (l15 & 7) << 4;
#pragma unroll 2
  for (int ks = 0; ks < 8; ++ks) {
    const int offk = ((ks * 64) + lg * 16) ^ xm;
    const bf16x8 a0 = *(const bf16x8*)(aggB + rb0 + offk);
    const bf16x8 a1 = *(const bf16x8*)(aggB + rb0 + 8192 + offk);
#pragma unroll
    for (int c = 0; c < 4; ++c) {
      const u32x4 bw = wbL[ks * 1024 + c * 64];
      const bf16x8 b = __builtin_bit_cast(bf16x8, bw);
      acc[0][c] = __builtin_amdgcn_mfma_f32_16x16x32_bf16(a0, b, acc[0][c], 0, 0, 0);
      acc[1][c] = __builtin_amdgcn_mfma_f32_16x16x32_bf16(a1, b, acc[1][c], 0, 0, 0);
    }
  }

  // rowmax -> per-row scale
#pragma unroll
  for (int rt = 0; rt < 2; ++rt)
#pragma unroll
    for (int j = 0; j < 4; ++j) {
      float m = 0.f;
#pragma unroll
      for (int c = 0; c < 4; ++c) m = fmaxf(m, fabsf(acc[rt][c][j]));
      m = fmaxf(m, __shfl_xor(m, 1)); m = fmaxf(m, __shfl_xor(m, 2));
      m = fmaxf(m, __shfl_xor(m, 4)); m = fmaxf(m, __shfl_xor(m, 8));
      redS[wv][rt * 16 + lg * 4 + j] = m;
    }
  __syncthreads();
  if (tid < 32) {
    float m = fmaxf(fmaxf(redS[0][tid], redS[1][tid]),
                    fmaxf(redS[2][tid], redS[3][tid]));
    m = fmaxf(m, 1e-20f);
    scale[blk * 32 + tid] = m * (1.0f / 127.0f);
    invSS[tid] = 127.0f / m;
  }
  __syncthreads();

  // quantize into LDS u8 tile (XOR-swizzled): biased u8 = floor(x*inv + 128.5)
  u8* qS = (u8*)aS;
#pragma unroll
  for (int rt = 0; rt < 2; ++rt)
#pragma unroll
    for (int j = 0; j < 4; ++j) {
      const int r = rt * 16 + lg * 4 + j;
      const float inv = invSS[r];
      const int sw = ((r >> 2) & 7) << 5;
#pragma unroll
      for (int c = 0; c < 4; ++c) {
        float t = fmaf(acc[rt][c][j], inv, 128.5f);
        t = fminf(255.f, fmaxf(1.f, t));
        qS[r * 256 + ((wv * 64 + c * 16 + l15) ^ sw)] = (u8)(u32)t;
      }
    }
  __syncthreads();

  // coalesced 16B stores of the 8KB quant tile
  const u32x4* q4 = (const u32x4*)aS;
  u32x4* yg = (u32x4*)(Yq + (size_t)blk * 8192);
#pragma unroll
  for (int q = 0; q < 2; ++q) {
    const int f = q * 4096 + tid * 16;         // byte index in tile
    const int row = f >> 8, col = f & 255;
    const int colx = col ^ (((row >> 2) & 7) << 5);
    __builtin_nontemporal_store(q4[(row * 256 + colx) >> 4], (u32x4*)&yg[f >> 4]);
  }
}

// ---- Kernel 3: gather-mean (int8 Y-space) + leaky + L2-normalize ----
// R5 structure verbatim: one wave per node, 4B/lane, 17 loads in flight,
// VGPR ~28. Proven 70 us (random-fill BW wall ~2.8 TB/s).
__global__ __launch_bounds__(256) void gather_kernel(const u8* __restrict__ Yq,
                                                     const float* __restrict__ scale,
                                                     const int* __restrict__ nbr,
                                                     float* __restrict__ out) {
  const int tid = threadIdx.x;
  const int lane = tid & 63, wv = tid >> 6;
  const int node = __builtin_amdgcn_readfirstlane(blockIdx.x * 4 + wv);

  const int il = nbr[node * KNBR + (lane & 15)];
  const float vscale = scale[il];
  const float sself = scale[node];
  const u32* yb = (const u32*)Yq;

  u32 v[17];
  v[0] = yb[(size_t)node * 64 + lane];
#pragma unroll
  for (int j = 0; j < 16; ++j) {
    const int r = __builtin_amdgcn_readlane(il, j);
    v[j + 1] = yb[(size_t)r * 64 + lane];
  }

  float a0, a1, a2, a3, S = sself;
  {
    float f0, f1, f2, f3;
    asm("v_cvt_f32_ubyte0 %0, %1" : "=v"(f0) : "v"(v[0]));
    asm("v_cvt_f32_ubyte1 %0, %1" : "=v"(f1) : "v"(v[0]));
    asm("v_cvt_f32_ubyte2 %0, %1" : "=v"(f2) : "v"(v[0]));
    asm("v_cvt_f32_ubyte3 %0, %1" : "=v"(f3) : "v"(v[0]));
    a0 = sself * f0; a1 = sself * f1; a2 = sself * f2; a3 = sself * f3;
  }
#pragma unroll
  for (int j = 0; j < 16; ++j) {
    const float s = __builtin_bit_cast(
        float, __builtin_amdgcn_readlane(__builtin_bit_cast(int, vscale), j));
    float f0, f1, f2, f3;
    asm("v_cvt_f32_ubyte0 %0, %1" : "=v"(f0) : "v"(v[j + 1]));
    asm("v_cvt_f32_ubyte1 %0, %1" : "=v"(f1) : "v"(v[j + 1]));
    asm("v_cvt_f32_ubyte2 %0, %1" : "=v"(f2) : "v"(v[j + 1]));
    asm("v_cvt_f32_ubyte3 %0, %1" : "=v"(f3) : "v"(v[j + 1]));
    S += s;
    a0 = fmaf(s, f0, a0); a1 = fmaf(s, f1, a1);
    a2 = fmaf(s, f2, a2); a3 = fmaf(s, f3, a3);
  }
  const float sc = 1.0f / 17.0f, bias = 128.0f * S;
  a0 = (a0 - bias) * sc; a1 = (a1 - bias) * sc;
  a2 = (a2 - bias) * sc; a3 = (a3 - bias) * sc;
  a0 = (a0 >= 0.f) ? a0 : ALPHA * a0;
  a1 = (a1 >= 0.f) ? a1 : ALPHA * a1;
  a2 = (a2 >= 0.f) ? a2 : ALPHA * a2;
  a3 = (a3 >= 0.f) ? a3 : ALPHA * a3;

  float ss = a0 * a0 + a1 * a1 + a2 * a2 + a3 * a3;
  ss += __shfl_xor(ss, 1);  ss += __shfl_xor(ss, 2);
  ss += __shfl_xor(ss, 4);  ss += __shfl_xor(ss, 8);
  ss += __shfl_xor(ss, 16); ss += __shfl_xor(ss, 32);
  const float inv = 1.0f / fmaxf(sqrtf(ss), 1e-12f);

  f32x4 o = {a0 * inv, a1 * inv, a2 * inv, a3 * inv};
  __builtin_nontemporal_store(o, (f32x4*)(out + (size_t)node * 256 + lane * 4));
}

extern "C" void kernel_launch(void* const* d_in, const int* in_sizes, int n_in,
                              void* d_out, int out_size, void* d_ws, size_t ws_size,
                              hipStream_t stream) {
  const float* h = (const float*)d_in[0];
  const int* nbr = (const int*)d_in[1];
  const float* W = (const float*)d_in[2];
  float* out = (float*)d_out;

  char* ws = (char*)d_ws;
  u16* Wb = (u16*)ws;                               // 128 KB fragment-ordered W
  float* scale = (float*)(ws + (1 << 17));          // ~400 KB f32 row scales
  u8* Yq = (u8*)(ws + (1 << 20));                   // 25.6 MB int8 Y

  prep_w_kernel<<<32, 256, 0, stream>>>(W, Wb);
  gemm_kernel<<<N_NODES / 32, 256, 0, stream>>>(h, Wb, Yq, scale);
  gather_kernel<<<N_NODES / 4, 256, 0, stream>>>(Yq, scale, nbr, out);
}